// Round 5
// baseline (116.007 us; speedup 1.0000x reference)
//
#include <hip/hip_runtime.h>
#include <math.h>

// Tropical (max-plus) depthwise conv2d, 5x5, stride 1, pad 2, dilation 1.
// x: (8,32,224,224) f32, kernel: (32,1,5,5) f32, out: (8,32,224,224) f32.
// out[b,c,h,w] = max_{i,j} x[b,c,h-2+i, w-2+j] + kernel[c,0,4-i,4-j]
//
// R11: split-stage pipeline (T3 2-phase) on R10's 36-row tile.
//   stage chunk0 (tile rows 0..19) -> barrier ->
//   issue chunk1 (rows 20..35)     -> compute+store tile0 (rows 0..19)
//   -> barrier (drains chunk1)     -> compute+store tile1 (rows 16..35).
// Chunk1's HBM time (~2.3us/CU/round) hides under tile0 compute
// (~2.5us/CU/round): breaks the global stage/compute oscillation that
// kept conv at ~4.3 TB/s effective (27us vs ~17.5us memory floor).
// LDS layout, staging instr (global_load_lds 16B), swizzle, max3 nesting,
// NT stores all unchanged from R9/R10 (proven or neutral).

#define TC_B 8
#define TC_C 32
#define TC_H 224
#define TC_W 224
#define TC_WQ 56          // f4 per image row
#define TC_HG 7           // 224/32 row-groups
#define T_ROWS 36         // 32 data + 2+2 halo rows
#define ROW_F4 65         // LDS row stride in float4
#define ROW_FL (ROW_F4 * 4)
#define NWG (TC_B * TC_C * TC_HG)   // 1792
#define NXCD 8
#define WPX (NWG / NXCD)            // 224, exact

typedef float f4v __attribute__((ext_vector_type(4)));  // NT-store-legal

__device__ __forceinline__ void stage_row_16B(
    const float* __restrict__ xp, float* tile, int r, int g, int cl, int lane) {
  const float NEG = -INFINITY;
  float* ldsrow = &tile[r * ROW_FL + 4];          // f4 index 1 (uniform base)
  if (g >= 0 && g < TC_H) {
    const float* gp = xp + (size_t)g * TC_W + cl * 4;
    // lane i -> LDS f4 index 1+i, holding x f4 col min(i,55)
    __builtin_amdgcn_global_load_lds(
        (const __attribute__((address_space(1))) void*)gp,
        (__attribute__((address_space(3))) void*)ldsrow, 16, 0, 0);
  } else {
    *(float4*)(ldsrow + (size_t)lane * 4) =
        make_float4(NEG, NEG, NEG, NEG);          // OOB row = -inf
  }
}

__device__ __forceinline__ void compute_store_tile(
    const float* tile, const float* w, float* op_base,
    int trow_base, int lane, bool redge) {
  const float NEG = -INFINITY;
  float acc[4][4];
  #pragma unroll
  for (int o = 0; o < 4; ++o)
    #pragma unroll
    for (int k = 0; k < 4; ++k) acc[o][k] = NEG;

  // tile row (trow_base + ri) holds this thread's input row (hbase-2+ri)
  #pragma unroll
  for (int ri = 0; ri < 8; ++ri) {
    const float* rp = &tile[(trow_base + ri) * ROW_FL + 4 * lane];
    const float4 A = *(const float4*)(rp);        // x cols 4l-4..4l-1 / -inf halo
    const float4 Bv = *(const float4*)(rp + 4);   // x cols 4l..4l+3
    const float4 Cv = *(const float4*)(rp + 8);   // x cols 4l+4..4l+7
    float v[12] = {A.x, A.y, A.z, A.w, Bv.x, Bv.y, Bv.z, Bv.w,
                   Cv.x, Cv.y, Cv.z, Cv.w};
    // right edge: f4 57 holds lane-spill garbage, taps use v[8],v[9] only
    v[8] = redge ? NEG : v[8];
    v[9] = redge ? NEG : v[9];

    #pragma unroll
    for (int o = 0; o < 4; ++o) {
      const int i = ri - o;                // weight row (compile-time)
      if (i < 0 || i > 4) continue;
      #pragma unroll
      for (int k = 0; k < 4; ++k) {
        const float t0 = v[2 + k] + w[i * 5 + 0];
        const float t1 = v[3 + k] + w[i * 5 + 1];
        const float t2 = v[4 + k] + w[i * 5 + 2];
        const float t3 = v[5 + k] + w[i * 5 + 3];
        const float t4 = v[6 + k] + w[i * 5 + 4];
        // max3-friendly nesting: (t0,t1,t2) and (t3,t4,acc) -> v_max3 pair
        acc[o][k] = fmaxf(fmaxf(fmaxf(t0, t1), t2),
                          fmaxf(fmaxf(t3, t4), acc[o][k]));
      }
    }
  }

  #pragma unroll
  for (int o = 0; o < 4; ++o) {
    f4v val = {acc[o][0], acc[o][1], acc[o][2], acc[o][3]};
    __builtin_nontemporal_store(val, (f4v*)(op_base + (size_t)o * TC_W) + lane);
  }
}

__global__ __launch_bounds__(256) void tropical_conv2d_kernel(
    const float* __restrict__ x, const float* __restrict__ kern,
    float* __restrict__ out) {
  const int tid = threadIdx.x;
  const int lane = tid & 63;
  const int yl = tid >> 6;          // wave 0..3

  // XCD-chunked swizzle: each XCD owns a contiguous range of logical tiles.
  const int orig = blockIdx.x;
  const int blk = (orig & (NXCD - 1)) * WPX + (orig >> 3);

  const int hg = blk % TC_HG;
  const int bc = blk / TC_HG;       // b*C + c (uniform)
  const int c = bc & (TC_C - 1);

  __shared__ float tile[T_ROWS * ROW_FL];   // 36*65*16 = 37440 B

  const float NEG = -INFINITY;
  const float4 NINF4 = make_float4(NEG, NEG, NEG, NEG);
  const float* xp = x + (size_t)bc * (TC_H * TC_W);
  const int g0 = hg * 32 - 2;       // global row of tile row 0

  // left-halo f4 (index 0) of every row = -inf; staging never writes f4 0.
  if (tid < T_ROWS) *(float4*)&tile[tid * ROW_FL] = NINF4;

  const int cl = lane < TC_WQ ? lane : TC_WQ - 1;   // clamp spill lanes

  // ---- chunk0: tile rows 0..19 (wave yl owns rows yl*5 .. yl*5+4) ----
  #pragma unroll
  for (int rr = 0; rr < 5; ++rr) {
    const int r = yl * 5 + rr;                      // wave-uniform
    stage_row_16B(xp, tile, r, g0 + r, cl, lane);
  }

  // weights while staging flies: c uniform -> scalar loads
  // w[i*5+j] = wflip[i][j] = kern[c][4-i][4-j]
  float w[25];
  #pragma unroll
  for (int q = 0; q < 25; ++q) w[q] = kern[c * 25 + 24 - q];

  __syncthreads();   // chunk0 resident (drains vmcnt + lgkmcnt)

  // ---- chunk1 issue: tile rows 20..35 (wave yl owns 20+yl*4 .. +3) ----
  // These fly during tile0 compute; LDS rows 20..35 are disjoint from
  // tile0's reads (rows 0..19).
  #pragma unroll
  for (int rr = 0; rr < 4; ++rr) {
    const int r = 20 + yl * 4 + rr;                 // wave-uniform
    stage_row_16B(xp, tile, r, g0 + r, cl, lane);
  }

  const bool active = (lane < TC_WQ);
  const bool redge = (lane == TC_WQ - 1);
  float* opb = out + (size_t)bc * (TC_H * TC_W);

  // ---- tile0: output rows hg*32 + yl*4 + (0..3), uses tile rows 0..19 ----
  if (active) {
    compute_store_tile(tile, w, opb + (size_t)(hg * 32 + yl * 4) * TC_W,
                       yl * 4, lane, redge);
  }

  __syncthreads();   // chunk1 resident

  // ---- tile1: output rows hg*32 + 16 + yl*4 + (0..3), tile rows 16..35 ----
  if (active) {
    compute_store_tile(tile, w, opb + (size_t)(hg * 32 + 16 + yl * 4) * TC_W,
                       16 + yl * 4, lane, redge);
  }
}

extern "C" void kernel_launch(void* const* d_in, const int* in_sizes, int n_in,
                              void* d_out, int out_size, void* d_ws, size_t ws_size,
                              hipStream_t stream) {
  const float* x = (const float*)d_in[0];
  const float* k = (const float*)d_in[1];
  float* out = (float*)d_out;

  dim3 block(256, 1, 1);
  dim3 grid(NWG, 1, 1);
  tropical_conv2d_kernel<<<grid, block, 0, stream>>>(x, k, out);
}